// Round 2
// baseline (4990.805 us; speedup 1.0000x reference)
//
#include <hip/hip_runtime.h>
#include <hip/hip_bf16.h>

// Problem constants: B=16, T=128, V=32000, E=256, H=512
#define NV 32000
#define NH 512
#define NE 256
#define NBT 2048   // B*T rows

typedef short bf16x8 __attribute__((ext_vector_type(8)));
typedef float f32x4  __attribute__((ext_vector_type(4)));

// ---------------- helpers ----------------

__device__ __forceinline__ void gload_lds16(const void* g, void* l) {
  __builtin_amdgcn_global_load_lds((const __attribute__((address_space(1))) void*)g,
                                   (__attribute__((address_space(3))) void*)l, 16, 0, 0);
}

// full-wave (64) f32 sum via DPP; total lands in lane 63.
__device__ __forceinline__ float wave_sum64(float v) {
  int x;
  x = __builtin_amdgcn_update_dpp(0, __float_as_int(v), 0x111, 0xf, 0xf, true); v += __int_as_float(x); // row_shr:1
  x = __builtin_amdgcn_update_dpp(0, __float_as_int(v), 0x112, 0xf, 0xf, true); v += __int_as_float(x); // row_shr:2
  x = __builtin_amdgcn_update_dpp(0, __float_as_int(v), 0x114, 0xf, 0xf, true); v += __int_as_float(x); // row_shr:4
  x = __builtin_amdgcn_update_dpp(0, __float_as_int(v), 0x118, 0xf, 0xf, true); v += __int_as_float(x); // row_shr:8
  x = __builtin_amdgcn_update_dpp(0, __float_as_int(v), 0x142, 0xa, 0xf, true); v += __int_as_float(x); // row_bcast:15 -> rows 1,3
  x = __builtin_amdgcn_update_dpp(0, __float_as_int(v), 0x143, 0xc, 0xf, true); v += __int_as_float(x); // row_bcast:31 -> rows 2,3
  return v;
}

// ---------------- kernel 1: fp32 -> bf16 convert (W_out) ----------------

__global__ void cvt_bf16(const float* __restrict__ s, __hip_bfloat16* __restrict__ d, int n4) {
  int i = blockIdx.x * blockDim.x + threadIdx.x;
  int st = gridDim.x * blockDim.x;
  for (; i < n4; i += st) {
    float4 v = ((const float4*)s)[i];
    ushort4 o;
    __hip_bfloat16 b0 = __float2bfloat16(v.x); o.x = *(unsigned short*)&b0;
    __hip_bfloat16 b1 = __float2bfloat16(v.y); o.y = *(unsigned short*)&b1;
    __hip_bfloat16 b2 = __float2bfloat16(v.z); o.z = *(unsigned short*)&b2;
    __hip_bfloat16 b3 = __float2bfloat16(v.w); o.w = *(unsigned short*)&b3;
    ((ushort4*)d)[i] = o;
  }
}

// ---------------- kernel 2: x_proj = emb[dec_inputs] @ W_ih^T + b_ih + b_hh ----------------
// block = 256 threads handles 8 rows x 512 cols; emb rows staged in LDS.

__global__ __launch_bounds__(256) void xproj_k(
    const int* __restrict__ tgt, const float* __restrict__ emb,
    const float* __restrict__ Wih, const float* __restrict__ bih,
    const float* __restrict__ bhh, float* __restrict__ xp)
{
  __shared__ float e[8][NE];
  const int tid = threadIdx.x;
  const int r0 = blockIdx.x * 8;
#pragma unroll
  for (int r = 0; r < 8; ++r) {
    int row = r0 + r;
    int b = row >> 7, t = row & 127;
    int tok = (t == 0) ? 1 : tgt[b * 128 + t - 1];   // SOS=1, else target[b][t-1]
    e[r][tid] = emb[(size_t)tok * NE + tid];
  }
  __syncthreads();
  const int j0 = tid, j1 = tid + 256;
  float a0[8] = {0,0,0,0,0,0,0,0}, a1[8] = {0,0,0,0,0,0,0,0};
  for (int k = 0; k < NE; k += 4) {
    float4 w0 = *(const float4*)(Wih + (size_t)j0 * NE + k);
    float4 w1 = *(const float4*)(Wih + (size_t)j1 * NE + k);
#pragma unroll
    for (int r = 0; r < 8; ++r) {
      float4 ev = *(const float4*)&e[r][k];
      a0[r] += w0.x*ev.x + w0.y*ev.y + w0.z*ev.z + w0.w*ev.w;
      a1[r] += w1.x*ev.x + w1.y*ev.y + w1.z*ev.z + w1.w*ev.w;
    }
  }
  float c0 = bih[j0] + bhh[j0];
  float c1 = bih[j1] + bhh[j1];
#pragma unroll
  for (int r = 0; r < 8; ++r) {
    xp[(size_t)(r0 + r) * NH + j0] = a0[r] + c0;
    xp[(size_t)(r0 + r) * NH + j1] = a1[r] + c1;
  }
}

// ---------------- kernel 3: tanh-RNN recurrence ----------------
// 128 blocks = 16 batches x 8 j-slices; blk%8 constant across a batch's partners
// (same XCD under round-robin dispatch). Each block holds its 64-row W_hh slab
// fully in VGPRs (32 floats/thread). Per-step pairwise sync via agent-scope flags.
// flags poison (0xAAAAAAAA) is negative -> "not done" semantics need no init.

__global__ __launch_bounds__(1024, 4) void rnn_rec(
    const float* __restrict__ h0src,   // encoder_hidden[0]: [16][512]
    const float* __restrict__ xp,      // [16*128][512] (b_ih+b_hh pre-added)
    const float* __restrict__ Whh,     // [512][512]
    float* __restrict__ hbuf,          // ws: [2][16][512]
    int* __restrict__ flags,           // ws: [16][8]
    __hip_bfloat16* __restrict__ hs,   // ws: [2048][512]
    float* __restrict__ hlast)         // d_out + 65536000: [16][512]
{
  const int blk = blockIdx.x;
  const int b = blk & 15, q = blk >> 4;     // q = j-slice 0..7
  const int tid = threadIdx.x;
  const int w = tid >> 6, l = tid & 63;
  const int k0 = l * 8;                     // this lane's k-slice
  const int jbase = q * 64 + w * 4;         // 4 rows per wave
  float wr[4][8];
#pragma unroll
  for (int r = 0; r < 4; ++r) {
    const float4* p = (const float4*)(Whh + (size_t)(jbase + r) * NH + k0);
    float4 a = p[0], c = p[1];
    wr[r][0]=a.x; wr[r][1]=a.y; wr[r][2]=a.z; wr[r][3]=a.w;
    wr[r][4]=c.x; wr[r][5]=c.y; wr[r][6]=c.z; wr[r][7]=c.w;
  }
  int* myflag = flags + b * 8 + q;
  for (int s = 0; s < 128; ++s) {
    const float* hsrc = (s == 0) ? (h0src + b * NH)
                                 : (hbuf + (size_t)((s & 1) * 16 + b) * NH);
    float4 h0 = *(const float4*)(hsrc + k0);
    float4 h1 = *(const float4*)(hsrc + k0 + 4);
    float hv[8] = {h0.x,h0.y,h0.z,h0.w,h1.x,h1.y,h1.z,h1.w};
    float acc0 = 0.f, acc1 = 0.f, acc2 = 0.f, acc3 = 0.f;
#pragma unroll
    for (int i = 0; i < 8; ++i) {
      acc0 = fmaf(wr[0][i], hv[i], acc0);
      acc1 = fmaf(wr[1][i], hv[i], acc1);
      acc2 = fmaf(wr[2][i], hv[i], acc2);
      acc3 = fmaf(wr[3][i], hv[i], acc3);
    }
    float s0 = wave_sum64(acc0);
    float s1 = wave_sum64(acc1);
    float s2 = wave_sum64(acc2);
    float s3 = wave_sum64(acc3);
    float t0 = __int_as_float(__builtin_amdgcn_readlane(__float_as_int(s0), 63));
    float t1 = __int_as_float(__builtin_amdgcn_readlane(__float_as_int(s1), 63));
    float t2 = __int_as_float(__builtin_amdgcn_readlane(__float_as_int(s2), 63));
    float t3 = __int_as_float(__builtin_amdgcn_readlane(__float_as_int(s3), 63));
    if (l < 4) {
      float pre = (l == 0) ? t0 : (l == 1) ? t1 : (l == 2) ? t2 : t3;
      int j = jbase + l;
      pre += xp[(size_t)(b * 128 + s) * NH + j];
      float h = tanhf(pre);
      hbuf[(size_t)(((s + 1) & 1) * 16 + b) * NH + j] = h;
      __hip_bfloat16 hb = __float2bfloat16(h);
      hs[(size_t)(b * 128 + s) * NH + j] = hb;
      if (s == 127) hlast[b * NH + j] = h;
    }
    if (s < 127) {
      __threadfence();                 // flush this thread's stores to device scope
      __syncthreads();                 // all stores flushed before flag
      if (tid == 0)
        __hip_atomic_store(myflag, s + 1, __ATOMIC_RELEASE, __HIP_MEMORY_SCOPE_AGENT);
      if (tid < 8) {
        int cnt = 0;
        while (__hip_atomic_load(flags + b * 8 + tid, __ATOMIC_ACQUIRE,
                                 __HIP_MEMORY_SCOPE_AGENT) <= s) {
          __builtin_amdgcn_s_sleep(2);
          if (++cnt > (1 << 17)) break;  // safety valve: fail loud, never hang
        }
      }
      __syncthreads();                 // acquire done before next-step h loads
    }
  }
}

// ---------------- kernel 4: logits = hs @ W_out^T + b_out (bf16 MFMA) ----------------
// 128x128 tile, BK=64, 4 waves (2x2), 16x16x32 MFMA, global_load_lds staging with
// source-side XOR swizzle (G21), bijective XCD swizzle (4000 = 8*500).

__global__ __launch_bounds__(256, 2) void gemm_logits(
    const __hip_bfloat16* __restrict__ A,   // [2048][512]
    const __hip_bfloat16* __restrict__ Bw,  // [32000][512]
    const float* __restrict__ bias,         // [32000]
    float* __restrict__ C)                  // [2048][32000]
{
  __shared__ __hip_bfloat16 As[128 * 64];
  __shared__ __hip_bfloat16 Bs[128 * 64];
  const int bid = blockIdx.x;
  const int wid = (bid & 7) * 500 + (bid >> 3);   // XCD-contiguous remap
  const int bm = wid & 15, bn = wid >> 4;
  const int m0 = bm * 128, n0 = bn * 128;
  const int tid = threadIdx.x;
  const int w = tid >> 6, l = tid & 63;
  const int wm = w & 1, wn = w >> 1;
  const int rs = tid >> 3;             // 0..31: row within a 32-row staging issue
  const int cb = (tid & 7) * 16;       // byte col within 128B row
  f32x4 acc[4][4] = {};

  for (int k0 = 0; k0 < NH; k0 += 64) {
    __syncthreads();
#pragma unroll
    for (int is = 0; is < 4; ++is) {
      int r = is * 32 + rs;
      int cbs = cb ^ ((r & 7) << 4);   // inverse-swizzled source (involution)
      gload_lds16(A + (size_t)(m0 + r) * NH + k0 + (cbs >> 1),
                  (char*)As + is * 4096 + w * 1024);
      gload_lds16(Bw + (size_t)(n0 + r) * NH + k0 + (cbs >> 1),
                  (char*)Bs + is * 4096 + w * 1024);
    }
    __syncthreads();   // compiler drains vmcnt before barrier
#pragma unroll
    for (int kk = 0; kk < 2; ++kk) {
      bf16x8 af[4], bfr[4];
      const int cbl = kk * 64 + (l >> 4) * 16;
#pragma unroll
      for (int mt = 0; mt < 4; ++mt) {
        int row = wm * 64 + mt * 16 + (l & 15);
        af[mt] = *(const bf16x8*)((const char*)As + row * 128 + (cbl ^ ((row & 7) << 4)));
      }
#pragma unroll
      for (int nt = 0; nt < 4; ++nt) {
        int row = wn * 64 + nt * 16 + (l & 15);
        bfr[nt] = *(const bf16x8*)((const char*)Bs + row * 128 + (cbl ^ ((row & 7) << 4)));
      }
#pragma unroll
      for (int mt = 0; mt < 4; ++mt)
#pragma unroll
        for (int nt = 0; nt < 4; ++nt)
          acc[mt][nt] = __builtin_amdgcn_mfma_f32_16x16x32_bf16(af[mt], bfr[nt], acc[mt][nt], 0, 0, 0);
    }
  }
  // epilogue: C/D layout col = lane&15, row = (lane>>4)*4 + reg (verified layout)
#pragma unroll
  for (int nt = 0; nt < 4; ++nt) {
    int n = n0 + wn * 64 + nt * 16 + (l & 15);
    float bv = bias[n];
#pragma unroll
    for (int mt = 0; mt < 4; ++mt) {
      int mbase = m0 + wm * 64 + mt * 16 + (l >> 4) * 4;
#pragma unroll
      for (int r2 = 0; r2 < 4; ++r2) {
        C[(size_t)(mbase + r2) * NV + n] = acc[mt][nt][r2] + bv;
      }
    }
  }
}

// ---------------- kernel 5: in-place log_softmax over V=32000 ----------------
// One block per row; row staged in 125KB LDS -> exactly one HBM read + one write.

__global__ __launch_bounds__(1024) void lsm(float* __restrict__ C) {
  __shared__ float buf[NV];
  __shared__ float red[17];
  const int tid = threadIdx.x;
  float4* Cv = (float4*)(C + (size_t)blockIdx.x * NV);
  float mx = -3.4e38f;
  for (int i = tid; i < NV / 4; i += 1024) {
    float4 v = Cv[i];
    ((float4*)buf)[i] = v;
    mx = fmaxf(mx, fmaxf(fmaxf(v.x, v.y), fmaxf(v.z, v.w)));
  }
#pragma unroll
  for (int off = 32; off; off >>= 1) mx = fmaxf(mx, __shfl_xor(mx, off));
  if ((tid & 63) == 0) red[tid >> 6] = mx;
  __syncthreads();
  if (tid == 0) {
    float m = red[0];
#pragma unroll
    for (int i = 1; i < 16; ++i) m = fmaxf(m, red[i]);
    red[16] = m;
  }
  __syncthreads();
  mx = red[16];
  float sm = 0.f;
  for (int i = tid; i < NV / 4; i += 1024) {
    float4 v = ((float4*)buf)[i];
    sm += __expf(v.x - mx) + __expf(v.y - mx) + __expf(v.z - mx) + __expf(v.w - mx);
  }
#pragma unroll
  for (int off = 32; off; off >>= 1) sm += __shfl_xor(sm, off);
  if ((tid & 63) == 0) red[tid >> 6] = sm;
  __syncthreads();
  if (tid == 0) {
    float t = 0.f;
#pragma unroll
    for (int i = 0; i < 16; ++i) t += red[i];
    red[16] = mx + __logf(t);
  }
  __syncthreads();
  const float lse = red[16];
  for (int i = tid; i < NV / 4; i += 1024) {
    float4 v = ((float4*)buf)[i];
    v.x -= lse; v.y -= lse; v.z -= lse; v.w -= lse;
    Cv[i] = v;
  }
}

// ---------------- launcher ----------------

extern "C" void kernel_launch(void* const* d_in, const int* in_sizes, int n_in,
                              void* d_out, int out_size, void* d_ws, size_t ws_size,
                              hipStream_t stream) {
  const float* enc_hid = (const float*)d_in[1];   // [1,16,512]
  const int*   tgt     = (const int*)d_in[2];     // [16,128]
  const float* emb     = (const float*)d_in[3];   // [32000,256]
  const float* Wih     = (const float*)d_in[4];   // [512,256]
  const float* Whh     = (const float*)d_in[5];   // [512,512]
  const float* bih     = (const float*)d_in[6];   // [512]
  const float* bhh     = (const float*)d_in[7];   // [512]
  const float* Wout    = (const float*)d_in[8];   // [32000,512]
  const float* bout    = (const float*)d_in[9];   // [32000]
  float* out = (float*)d_out;                     // [16*128*32000] + [16*512]

  char* ws = (char*)d_ws;
  __hip_bfloat16* woutb = (__hip_bfloat16*)ws;                        // 32,768,000 B
  float*          xp    = (float*)(ws + 32768000);                    //  4,194,304 B
  __hip_bfloat16* hs    = (__hip_bfloat16*)(ws + 32768000 + 4194304); //  2,097,152 B
  float*          hbuf  = (float*)(ws + 32768000 + 4194304 + 2097152);//     65,536 B
  int*            flags = (int*)(ws + 32768000 + 4194304 + 2097152 + 65536); // 512 B
  float*          hlast = out + (size_t)65536000;

  hipLaunchKernelGGL(cvt_bf16,   dim3(2048), dim3(256), 0, stream, Wout, woutb, NV * NH / 4);
  hipLaunchKernelGGL(xproj_k,    dim3(256),  dim3(256), 0, stream, tgt, emb, Wih, bih, bhh, xp);
  hipLaunchKernelGGL(rnn_rec,    dim3(128),  dim3(1024), 0, stream, enc_hid, xp, Whh, hbuf, flags, hs, hlast);
  hipLaunchKernelGGL(gemm_logits, dim3(4000), dim3(256), 0, stream, hs, woutb, bout, out);
  hipLaunchKernelGGL(lsm,        dim3(2048), dim3(1024), 0, stream, out);
}

// Round 4
// 1213.648 us; speedup vs baseline: 4.1122x; 4.1122x over previous
//
#include <hip/hip_runtime.h>
#include <hip/hip_bf16.h>

// Problem constants: B=16, T=128, V=32000, E=256, H=512
#define NV 32000
#define NH 512
#define NE 256
#define NBT 2048   // B*T rows

typedef short bf16x8 __attribute__((ext_vector_type(8)));
typedef float f32x4  __attribute__((ext_vector_type(4)));

// ---------------- helpers ----------------

__device__ __forceinline__ void gload_lds16(const void* g, void* l) {
  __builtin_amdgcn_global_load_lds((const __attribute__((address_space(1))) void*)g,
                                   (__attribute__((address_space(3))) void*)l, 16, 0, 0);
}

// full-wave (64) f32 sum via DPP; total lands in lane 63.
__device__ __forceinline__ float wave_sum64(float v) {
  int x;
  x = __builtin_amdgcn_update_dpp(0, __float_as_int(v), 0x111, 0xf, 0xf, true); v += __int_as_float(x); // row_shr:1
  x = __builtin_amdgcn_update_dpp(0, __float_as_int(v), 0x112, 0xf, 0xf, true); v += __int_as_float(x); // row_shr:2
  x = __builtin_amdgcn_update_dpp(0, __float_as_int(v), 0x114, 0xf, 0xf, true); v += __int_as_float(x); // row_shr:4
  x = __builtin_amdgcn_update_dpp(0, __float_as_int(v), 0x118, 0xf, 0xf, true); v += __int_as_float(x); // row_shr:8
  x = __builtin_amdgcn_update_dpp(0, __float_as_int(v), 0x142, 0xa, 0xf, true); v += __int_as_float(x); // row_bcast:15 -> rows 1,3
  x = __builtin_amdgcn_update_dpp(0, __float_as_int(v), 0x143, 0xc, 0xf, true); v += __int_as_float(x); // row_bcast:31 -> rows 2,3
  return v;
}

// ---------------- kernel 1: fp32 -> bf16 convert (W_out) ----------------

__global__ void cvt_bf16(const float* __restrict__ s, __hip_bfloat16* __restrict__ d, int n4) {
  int i = blockIdx.x * blockDim.x + threadIdx.x;
  int st = gridDim.x * blockDim.x;
  for (; i < n4; i += st) {
    float4 v = ((const float4*)s)[i];
    ushort4 o;
    __hip_bfloat16 b0 = __float2bfloat16(v.x); o.x = *(unsigned short*)&b0;
    __hip_bfloat16 b1 = __float2bfloat16(v.y); o.y = *(unsigned short*)&b1;
    __hip_bfloat16 b2 = __float2bfloat16(v.z); o.z = *(unsigned short*)&b2;
    __hip_bfloat16 b3 = __float2bfloat16(v.w); o.w = *(unsigned short*)&b3;
    ((ushort4*)d)[i] = o;
  }
}

// ---------------- kernel 2: x_proj = emb[dec_inputs] @ W_ih^T + b_ih + b_hh ----------------

__global__ __launch_bounds__(256) void xproj_k(
    const int* __restrict__ tgt, const float* __restrict__ emb,
    const float* __restrict__ Wih, const float* __restrict__ bih,
    const float* __restrict__ bhh, float* __restrict__ xp)
{
  __shared__ float e[8][NE];
  const int tid = threadIdx.x;
  const int r0 = blockIdx.x * 8;
#pragma unroll
  for (int r = 0; r < 8; ++r) {
    int row = r0 + r;
    int b = row >> 7, t = row & 127;
    int tok = (t == 0) ? 1 : tgt[b * 128 + t - 1];   // SOS=1, else target[b][t-1]
    e[r][tid] = emb[(size_t)tok * NE + tid];
  }
  __syncthreads();
  const int j0 = tid, j1 = tid + 256;
  float a0[8] = {0,0,0,0,0,0,0,0}, a1[8] = {0,0,0,0,0,0,0,0};
  for (int k = 0; k < NE; k += 4) {
    float4 w0 = *(const float4*)(Wih + (size_t)j0 * NE + k);
    float4 w1 = *(const float4*)(Wih + (size_t)j1 * NE + k);
#pragma unroll
    for (int r = 0; r < 8; ++r) {
      float4 ev = *(const float4*)&e[r][k];
      a0[r] += w0.x*ev.x + w0.y*ev.y + w0.z*ev.z + w0.w*ev.w;
      a1[r] += w1.x*ev.x + w1.y*ev.y + w1.z*ev.z + w1.w*ev.w;
    }
  }
  float c0 = bih[j0] + bhh[j0];
  float c1 = bih[j1] + bhh[j1];
#pragma unroll
  for (int r = 0; r < 8; ++r) {
    xp[(size_t)(r0 + r) * NH + j0] = a0[r] + c0;
    xp[(size_t)(r0 + r) * NH + j1] = a1[r] + c1;
  }
}

// ---------------- kernel 3: tanh-RNN recurrence ----------------
// 128 blocks = 16 batches x 8 j-slices. Each block's 64-row W_hh slab in regs.
// Cross-block exchange entirely via RELAXED agent-scope atomics (coherence-point
// ops, no buffer_inv/wbl2 cache maintenance). Ordering: data-store completion is
// guaranteed by explicit s_waitcnt vmcnt(0) per thread + barrier BEFORE the flag
// store; consumer reads are coherence-point loads so no acquire fence is needed.

__global__ __launch_bounds__(1024, 4) void rnn_rec(
    const float* __restrict__ h0src,   // encoder_hidden[0]: [16][512]
    const float* __restrict__ xp,      // [16*128][512] (b_ih+b_hh pre-added)
    const float* __restrict__ Whh,     // [512][512]
    float* __restrict__ hbuf,          // ws: [2][16][512]
    int* __restrict__ flags,           // ws: [16][8]  (poison 0xAA.. < 1)
    __hip_bfloat16* __restrict__ hs,   // ws: [2048][512]
    float* __restrict__ hlast)         // d_out + 65536000: [16][512]
{
  const int blk = blockIdx.x;
  const int b = blk & 15, q = blk >> 4;     // q = j-slice 0..7
  const int tid = threadIdx.x;
  const int w = tid >> 6, l = tid & 63;
  const int k0 = l * 8;                     // this lane's k-slice
  const int jbase = q * 64 + w * 4;         // 4 rows per wave
  float wr[4][8];
#pragma unroll
  for (int r = 0; r < 4; ++r) {
    const float4* p = (const float4*)(Whh + (size_t)(jbase + r) * NH + k0);
    float4 a = p[0], c = p[1];
    wr[r][0]=a.x; wr[r][1]=a.y; wr[r][2]=a.z; wr[r][3]=a.w;
    wr[r][4]=c.x; wr[r][5]=c.y; wr[r][6]=c.z; wr[r][7]=c.w;
  }
  int* myflag = flags + b * 8 + q;
  for (int s = 0; s < 128; ++s) {
    float hv[8];
    if (s == 0) {
      const float* hsrc = h0src + b * NH + k0;
      float4 h0 = *(const float4*)(hsrc);
      float4 h1 = *(const float4*)(hsrc + 4);
      hv[0]=h0.x; hv[1]=h0.y; hv[2]=h0.z; hv[3]=h0.w;
      hv[4]=h1.x; hv[5]=h1.y; hv[6]=h1.z; hv[7]=h1.w;
    } else {
      const float* hb = hbuf + (size_t)((s & 1) * 16 + b) * NH + k0;
#pragma unroll
      for (int i = 0; i < 8; ++i)
        hv[i] = __hip_atomic_load(hb + i, __ATOMIC_RELAXED, __HIP_MEMORY_SCOPE_AGENT);
    }
    float acc0 = 0.f, acc1 = 0.f, acc2 = 0.f, acc3 = 0.f;
#pragma unroll
    for (int i = 0; i < 8; ++i) {
      acc0 = fmaf(wr[0][i], hv[i], acc0);
      acc1 = fmaf(wr[1][i], hv[i], acc1);
      acc2 = fmaf(wr[2][i], hv[i], acc2);
      acc3 = fmaf(wr[3][i], hv[i], acc3);
    }
    float s0 = wave_sum64(acc0);
    float s1 = wave_sum64(acc1);
    float s2 = wave_sum64(acc2);
    float s3 = wave_sum64(acc3);
    float t0 = __int_as_float(__builtin_amdgcn_readlane(__float_as_int(s0), 63));
    float t1 = __int_as_float(__builtin_amdgcn_readlane(__float_as_int(s1), 63));
    float t2 = __int_as_float(__builtin_amdgcn_readlane(__float_as_int(s2), 63));
    float t3 = __int_as_float(__builtin_amdgcn_readlane(__float_as_int(s3), 63));
    if (l < 4) {
      float pre = (l == 0) ? t0 : (l == 1) ? t1 : (l == 2) ? t2 : t3;
      int j = jbase + l;
      pre += xp[(size_t)(b * 128 + s) * NH + j];
      float h = tanhf(pre);
      if (s < 127)
        __hip_atomic_store(hbuf + (size_t)(((s + 1) & 1) * 16 + b) * NH + j, h,
                           __ATOMIC_RELAXED, __HIP_MEMORY_SCOPE_AGENT);
      hs[(size_t)(b * 128 + s) * NH + j] = __float2bfloat16(h);
      if (s == 127) hlast[b * NH + j] = h;
    }
    if (s < 127) {
      // ensure this thread's coherence-point stores have completed
      asm volatile("s_waitcnt vmcnt(0)" ::: "memory");
      __syncthreads();                 // all threads' stores completed before flag
      if (tid == 0)
        __hip_atomic_store(myflag, s + 1, __ATOMIC_RELAXED, __HIP_MEMORY_SCOPE_AGENT);
      if (tid < 8) {
        int cnt = 0;
        while (__hip_atomic_load(flags + b * 8 + tid, __ATOMIC_RELAXED,
                                 __HIP_MEMORY_SCOPE_AGENT) <= s) {
          __builtin_amdgcn_s_sleep(1);
          if (++cnt > (1 << 15)) break;  // safety valve: fail loud, never hang
        }
      }
      __syncthreads();                 // poll success visible to whole block
    }
  }
}

// ---------------- kernel 4: logits = hs @ W_out^T + b_out (bf16 MFMA) ----------------
// 128x128 tile, BK=64, 4 waves (2x2), 16x16x32 MFMA, global_load_lds staging with
// source-side XOR swizzle (G21), bijective XCD swizzle (4000 = 8*500).

__global__ __launch_bounds__(256, 2) void gemm_logits(
    const __hip_bfloat16* __restrict__ A,   // [2048][512]
    const __hip_bfloat16* __restrict__ Bw,  // [32000][512]
    const float* __restrict__ bias,         // [32000]
    float* __restrict__ C)                  // [2048][32000]
{
  __shared__ __hip_bfloat16 As[128 * 64];
  __shared__ __hip_bfloat16 Bs[128 * 64];
  const int bid = blockIdx.x;
  const int wid = (bid & 7) * 500 + (bid >> 3);   // XCD-contiguous remap
  const int bm = wid & 15, bn = wid >> 4;
  const int m0 = bm * 128, n0 = bn * 128;
  const int tid = threadIdx.x;
  const int w = tid >> 6, l = tid & 63;
  const int wm = w & 1, wn = w >> 1;
  const int rs = tid >> 3;             // 0..31: row within a 32-row staging issue
  const int cb = (tid & 7) * 16;       // byte col within 128B row
  f32x4 acc[4][4] = {};

  for (int k0 = 0; k0 < NH; k0 += 64) {
    __syncthreads();
#pragma unroll
    for (int is = 0; is < 4; ++is) {
      int r = is * 32 + rs;
      int cbs = cb ^ ((r & 7) << 4);   // inverse-swizzled source (involution)
      gload_lds16(A + (size_t)(m0 + r) * NH + k0 + (cbs >> 1),
                  (char*)As + is * 4096 + w * 1024);
      gload_lds16(Bw + (size_t)(n0 + r) * NH + k0 + (cbs >> 1),
                  (char*)Bs + is * 4096 + w * 1024);
    }
    __syncthreads();   // compiler drains vmcnt before barrier
#pragma unroll
    for (int kk = 0; kk < 2; ++kk) {
      bf16x8 af[4], bfr[4];
      const int cbl = kk * 64 + (l >> 4) * 16;
#pragma unroll
      for (int mt = 0; mt < 4; ++mt) {
        int row = wm * 64 + mt * 16 + (l & 15);
        af[mt] = *(const bf16x8*)((const char*)As + row * 128 + (cbl ^ ((row & 7) << 4)));
      }
#pragma unroll
      for (int nt = 0; nt < 4; ++nt) {
        int row = wn * 64 + nt * 16 + (l & 15);
        bfr[nt] = *(const bf16x8*)((const char*)Bs + row * 128 + (cbl ^ ((row & 7) << 4)));
      }
#pragma unroll
      for (int mt = 0; mt < 4; ++mt)
#pragma unroll
        for (int nt = 0; nt < 4; ++nt)
          acc[mt][nt] = __builtin_amdgcn_mfma_f32_16x16x32_bf16(af[mt], bfr[nt], acc[mt][nt], 0, 0, 0);
    }
  }
  // epilogue: C/D layout col = lane&15, row = (lane>>4)*4 + reg (verified layout)
#pragma unroll
  for (int nt = 0; nt < 4; ++nt) {
    int n = n0 + wn * 64 + nt * 16 + (l & 15);
    float bv = bias[n];
#pragma unroll
    for (int mt = 0; mt < 4; ++mt) {
      int mbase = m0 + wm * 64 + mt * 16 + (l >> 4) * 4;
#pragma unroll
      for (int r2 = 0; r2 < 4; ++r2) {
        C[(size_t)(mbase + r2) * NV + n] = acc[mt][nt][r2] + bv;
      }
    }
  }
}

// ---------------- kernel 5: in-place log_softmax over V=32000 ----------------

__global__ __launch_bounds__(1024) void lsm(float* __restrict__ C) {
  __shared__ float buf[NV];
  __shared__ float red[17];
  const int tid = threadIdx.x;
  float4* Cv = (float4*)(C + (size_t)blockIdx.x * NV);
  float mx = -3.4e38f;
  for (int i = tid; i < NV / 4; i += 1024) {
    float4 v = Cv[i];
    ((float4*)buf)[i] = v;
    mx = fmaxf(mx, fmaxf(fmaxf(v.x, v.y), fmaxf(v.z, v.w)));
  }
#pragma unroll
  for (int off = 32; off; off >>= 1) mx = fmaxf(mx, __shfl_xor(mx, off));
  if ((tid & 63) == 0) red[tid >> 6] = mx;
  __syncthreads();
  if (tid == 0) {
    float m = red[0];
#pragma unroll
    for (int i = 1; i < 16; ++i) m = fmaxf(m, red[i]);
    red[16] = m;
  }
  __syncthreads();
  mx = red[16];
  float sm = 0.f;
  for (int i = tid; i < NV / 4; i += 1024) {
    float4 v = ((float4*)buf)[i];
    sm += __expf(v.x - mx) + __expf(v.y - mx) + __expf(v.z - mx) + __expf(v.w - mx);
  }
#pragma unroll
  for (int off = 32; off; off >>= 1) sm += __shfl_xor(sm, off);
  if ((tid & 63) == 0) red[tid >> 6] = sm;
  __syncthreads();
  if (tid == 0) {
    float t = 0.f;
#pragma unroll
    for (int i = 0; i < 16; ++i) t += red[i];
    red[16] = mx + __logf(t);
  }
  __syncthreads();
  const float lse = red[16];
  for (int i = tid; i < NV / 4; i += 1024) {
    float4 v = ((float4*)buf)[i];
    v.x -= lse; v.y -= lse; v.z -= lse; v.w -= lse;
    Cv[i] = v;
  }
}

// ---------------- launcher ----------------

extern "C" void kernel_launch(void* const* d_in, const int* in_sizes, int n_in,
                              void* d_out, int out_size, void* d_ws, size_t ws_size,
                              hipStream_t stream) {
  const float* enc_hid = (const float*)d_in[1];   // [1,16,512]
  const int*   tgt     = (const int*)d_in[2];     // [16,128]
  const float* emb     = (const float*)d_in[3];   // [32000,256]
  const float* Wih     = (const float*)d_in[4];   // [512,256]
  const float* Whh     = (const float*)d_in[5];   // [512,512]
  const float* bih     = (const float*)d_in[6];   // [512]
  const float* bhh     = (const float*)d_in[7];   // [512]
  const float* Wout    = (const float*)d_in[8];   // [32000,512]
  const float* bout    = (const float*)d_in[9];   // [32000]
  float* out = (float*)d_out;                     // [16*128*32000] + [16*512]

  char* ws = (char*)d_ws;
  __hip_bfloat16* woutb = (__hip_bfloat16*)ws;                        // 32,768,000 B
  float*          xp    = (float*)(ws + 32768000);                    //  4,194,304 B
  __hip_bfloat16* hs    = (__hip_bfloat16*)(ws + 32768000 + 4194304); //  2,097,152 B
  float*          hbuf  = (float*)(ws + 32768000 + 4194304 + 2097152);//     65,536 B
  int*            flags = (int*)(ws + 32768000 + 4194304 + 2097152 + 65536); // 512 B
  float*          hlast = out + (size_t)65536000;

  hipLaunchKernelGGL(cvt_bf16,   dim3(2048), dim3(256), 0, stream, Wout, woutb, NV * NH / 4);
  hipLaunchKernelGGL(xproj_k,    dim3(256),  dim3(256), 0, stream, tgt, emb, Wih, bih, bhh, xp);
  hipLaunchKernelGGL(rnn_rec,    dim3(128),  dim3(1024), 0, stream, enc_hid, xp, Whh, hbuf, flags, hs, hlast);
  hipLaunchKernelGGL(gemm_logits, dim3(4000), dim3(256), 0, stream, hs, woutb, bout, out);
  hipLaunchKernelGGL(lsm,        dim3(2048), dim3(1024), 0, stream, out);
}